// Round 5
// baseline (349.369 us; speedup 1.0000x reference)
//
#include <hip/hip_runtime.h>
#include <cstddef>

#define D_MODEL 1024
#define D_STATE 16
#define DT_RANK 64
#define BATCH 4
#define SEQ 4096
#define NPROJ 96                 // DT_RANK + 2*D_STATE
#define M_TOTAL (BATCH * SEQ)    // 16384

__device__ __forceinline__ float softplus_fast(float v) {
    // max(v,0) + log(1+exp(-|v|)) — stable, hardware exp/log (err ~1e-6, thr=4.0)
    return fmaxf(v, 0.0f) + __logf(1.0f + __expf(-fabsf(v)));
}

// ---------------- GEMM1 (split-K): part[ks][m,p] = sum_{k in slice} x[m,k]*W[p,k]
// BM=64, BN=96, BK=32. 256 thr, 4x6/thread. grid (256, ksplit).
// xs row-major [64][36]: float4 staging writes conflict-free (8 lanes per
// 4-bank group), a-frag reads are 16-lane broadcasts on 4 distinct banks.
__global__ __launch_bounds__(256) void proj_part_kernel(const float* __restrict__ x,
                                                        const float* __restrict__ W,
                                                        float* __restrict__ part,
                                                        int kslice) {
    __shared__ float xs[64][36];      // [row][k] row-major
    __shared__ float ws_t[32][100];   // [k][col] transposed, b-frag = 3x ds_read_b64
    const int tid   = threadIdx.x;
    const int row0  = blockIdx.x * 64;
    const int kbase = blockIdx.y * kslice;
    const int ty = tid >> 4;   // 0..15 -> rows ty*4..+3
    const int tx = tid & 15;   // cols tx*6..+5

    float acc[4][6];
#pragma unroll
    for (int i = 0; i < 4; ++i)
#pragma unroll
        for (int j = 0; j < 6; ++j) acc[i][j] = 0.0f;

    for (int k0 = kbase; k0 < kbase + kslice; k0 += 32) {
        // stage x tile row-major: 64 rows x 32 k (512 float4, 2/thread)
        for (int i = tid; i < 64 * 8; i += 256) {
            int r = i >> 3, c4 = i & 7;
            float4 v = *reinterpret_cast<const float4*>(
                &x[(size_t)(row0 + r) * 1024 + k0 + c4 * 4]);
            *reinterpret_cast<float4*>(&xs[r][c4 * 4]) = v;
        }
        // stage W tile transposed: 96 cols x 32 k (768 float4, 3/thread)
        for (int i = tid; i < 96 * 8; i += 256) {
            int r = i >> 3, c4 = i & 7;
            float4 v = *reinterpret_cast<const float4*>(
                &W[(size_t)r * 1024 + k0 + c4 * 4]);
            ws_t[c4 * 4 + 0][r] = v.x; ws_t[c4 * 4 + 1][r] = v.y;
            ws_t[c4 * 4 + 2][r] = v.z; ws_t[c4 * 4 + 3][r] = v.w;
        }
        __syncthreads();
#pragma unroll 8
        for (int k = 0; k < 32; ++k) {
            float a[4];
#pragma unroll
            for (int i = 0; i < 4; ++i) a[i] = xs[ty * 4 + i][k];   // broadcast reads
            float2 b0 = *reinterpret_cast<const float2*>(&ws_t[k][tx * 6]);
            float2 b1 = *reinterpret_cast<const float2*>(&ws_t[k][tx * 6 + 2]);
            float2 b2 = *reinterpret_cast<const float2*>(&ws_t[k][tx * 6 + 4]);
            float b[6] = {b0.x, b0.y, b1.x, b1.y, b2.x, b2.y};
#pragma unroll
            for (int i = 0; i < 4; ++i)
#pragma unroll
                for (int j = 0; j < 6; ++j) acc[i][j] = fmaf(a[i], b[j], acc[i][j]);
        }
        __syncthreads();
    }
    size_t base = ((size_t)blockIdx.y * M_TOTAL + row0) * NPROJ;
#pragma unroll
    for (int i = 0; i < 4; ++i) {
        size_t rbase = base + (size_t)(ty * 4 + i) * NPROJ + tx * 6;
#pragma unroll
        for (int j = 0; j < 6; ++j) part[rbase + j] = acc[i][j];
    }
}

// ---------------- reduce: xp = sum_ks part[ks]  (float4 grid) ----------------
__global__ __launch_bounds__(256) void reduce_xp_kernel(const float* __restrict__ part,
                                                        float* __restrict__ xp,
                                                        int ksplit) {
    const size_t stride4 = (size_t)M_TOTAL * NPROJ / 4;
    size_t i = (size_t)blockIdx.x * 256 + threadIdx.x;
    const float4* p = reinterpret_cast<const float4*>(part);
    float4 a = p[i];
    for (int s = 1; s < ksplit; ++s) {
        float4 b = p[i + (size_t)s * stride4];
        a.x += b.x; a.y += b.y; a.z += b.z; a.w += b.w;
    }
    reinterpret_cast<float4*>(xp)[i] = a;
}

// ------- GEMM2: delta[m,d] = softplus( sum_r xp[m,r]*Wd[d,r] + b_dt[d] ) ----
__global__ __launch_bounds__(256) void delta_kernel(const float* __restrict__ xp,
                                                    const float* __restrict__ Wd,
                                                    const float* __restrict__ b_dt,
                                                    float* __restrict__ delta) {
    __shared__ float as_t[32][132];  // [k][row]
    __shared__ float bs_t[32][132];  // [k][col]
    const int tid  = threadIdx.x;
    const int row0 = blockIdx.x * 128;
    const int col0 = blockIdx.y * 128;
    const int ty = tid >> 4;
    const int tx = tid & 15;

    float acc[8][8];
#pragma unroll
    for (int i = 0; i < 8; ++i)
#pragma unroll
        for (int j = 0; j < 8; ++j) acc[i][j] = 0.0f;

    for (int k0 = 0; k0 < 64; k0 += 32) {
        for (int i = tid; i < 128 * 8; i += 256) {
            int r = i >> 3, c4 = i & 7;
            float4 v = *reinterpret_cast<const float4*>(
                &xp[(size_t)(row0 + r) * NPROJ + k0 + c4 * 4]);
            as_t[c4 * 4 + 0][r] = v.x; as_t[c4 * 4 + 1][r] = v.y;
            as_t[c4 * 4 + 2][r] = v.z; as_t[c4 * 4 + 3][r] = v.w;
        }
        for (int i = tid; i < 128 * 8; i += 256) {
            int r = i >> 3, c4 = i & 7;
            float4 v = *reinterpret_cast<const float4*>(
                &Wd[(size_t)(col0 + r) * 64 + k0 + c4 * 4]);
            bs_t[c4 * 4 + 0][r] = v.x; bs_t[c4 * 4 + 1][r] = v.y;
            bs_t[c4 * 4 + 2][r] = v.z; bs_t[c4 * 4 + 3][r] = v.w;
        }
        __syncthreads();
#pragma unroll 4
        for (int k = 0; k < 32; ++k) {
            float4 a0 = *reinterpret_cast<const float4*>(&as_t[k][ty * 8]);
            float4 a1 = *reinterpret_cast<const float4*>(&as_t[k][ty * 8 + 4]);
            float4 b0 = *reinterpret_cast<const float4*>(&bs_t[k][tx * 8]);
            float4 b1 = *reinterpret_cast<const float4*>(&bs_t[k][tx * 8 + 4]);
            float a[8] = {a0.x, a0.y, a0.z, a0.w, a1.x, a1.y, a1.z, a1.w};
            float b[8] = {b0.x, b0.y, b0.z, b0.w, b1.x, b1.y, b1.z, b1.w};
#pragma unroll
            for (int i = 0; i < 8; ++i)
#pragma unroll
                for (int j = 0; j < 8; ++j) acc[i][j] = fmaf(a[i], b[j], acc[i][j]);
        }
        __syncthreads();
    }

    float4 bias0 = *reinterpret_cast<const float4*>(&b_dt[col0 + tx * 8]);
    float4 bias1 = *reinterpret_cast<const float4*>(&b_dt[col0 + tx * 8 + 4]);
#pragma unroll
    for (int i = 0; i < 8; ++i) {
        int row = row0 + ty * 8 + i;
        float4 o0, o1;
        o0.x = softplus_fast(acc[i][0] + bias0.x);
        o0.y = softplus_fast(acc[i][1] + bias0.y);
        o0.z = softplus_fast(acc[i][2] + bias0.z);
        o0.w = softplus_fast(acc[i][3] + bias0.w);
        o1.x = softplus_fast(acc[i][4] + bias1.x);
        o1.y = softplus_fast(acc[i][5] + bias1.y);
        o1.z = softplus_fast(acc[i][6] + bias1.z);
        o1.w = softplus_fast(acc[i][7] + bias1.w);
        float* dst = &delta[(size_t)row * D_MODEL + col0 + tx * 8];
        *reinterpret_cast<float4*>(dst)     = o0;
        *reinterpret_cast<float4*>(dst + 4) = o1;
    }
}

// ---------------- Scan pass A: per-chunk transfer (exp(Av*sum_dv), h_local) --
template<int CLEN_T>
__global__ __launch_bounds__(256) void scanA_kernel(const float* __restrict__ x,
                                                    const float* __restrict__ xp,
                                                    const float* __restrict__ delta,
                                                    const float* __restrict__ A_log,
                                                    float* __restrict__ P,
                                                    float* __restrict__ H) {
    const int chunk = blockIdx.x;
    const int b     = blockIdx.z;
    const int d     = blockIdx.y * 256 + threadIdx.x;

    float Av[16];
    const float4* Arow = reinterpret_cast<const float4*>(A_log + (size_t)d * D_STATE);
#pragma unroll
    for (int q = 0; q < 4; ++q) {
        float4 v = Arow[q];
        Av[q*4+0] = -__expf(v.x); Av[q*4+1] = -__expf(v.y);
        Av[q*4+2] = -__expf(v.z); Av[q*4+3] = -__expf(v.w);
    }
    float h[16];
#pragma unroll
    for (int n = 0; n < 16; ++n) h[n] = 0.0f;
    float sdv = 0.0f;

    const size_t m0 = (size_t)b * SEQ + (size_t)chunk * CLEN_T;
    const size_t xbase = m0 * D_MODEL + d;
    const size_t pbase = m0 * NPROJ + DT_RANK;

    float dv_c = delta[xbase];
    float xv_c = x[xbase];
#pragma unroll 4
    for (int j = 0; j < CLEN_T; ++j) {
        float dv_n = 0.0f, xv_n = 0.0f;
        if (j + 1 < CLEN_T) {                      // prefetch next step
            dv_n = delta[xbase + (size_t)(j + 1) * D_MODEL];
            xv_n = x[xbase + (size_t)(j + 1) * D_MODEL];
        }
        const float4* Bp = reinterpret_cast<const float4*>(xp + pbase + (size_t)j * NPROJ);
        float4 B0 = Bp[0], B1 = Bp[1], B2 = Bp[2], B3 = Bp[3];
        float Bv[16] = {B0.x,B0.y,B0.z,B0.w, B1.x,B1.y,B1.z,B1.w,
                        B2.x,B2.y,B2.z,B2.w, B3.x,B3.y,B3.z,B3.w};
        float dtx = dv_c * xv_c;
        sdv += dv_c;
#pragma unroll
        for (int n = 0; n < 16; ++n) {
            float a = __expf(dv_c * Av[n]);
            h[n] = fmaf(a, h[n], dtx * Bv[n]);
        }
        dv_c = dv_n; xv_c = xv_n;
    }
    size_t idx = (((size_t)chunk * BATCH + b) * D_MODEL + d) * D_STATE;
    float4* Pp = reinterpret_cast<float4*>(P + idx);
    float4* Hp = reinterpret_cast<float4*>(H + idx);
#pragma unroll
    for (int q = 0; q < 4; ++q) {
        float4 pv, hv;
        pv.x = __expf(Av[q*4+0] * sdv); pv.y = __expf(Av[q*4+1] * sdv);
        pv.z = __expf(Av[q*4+2] * sdv); pv.w = __expf(Av[q*4+3] * sdv);
        hv.x = h[q*4+0]; hv.y = h[q*4+1]; hv.z = h[q*4+2]; hv.w = h[q*4+3];
        Pp[q] = pv; Hp[q] = hv;
    }
}

// ---------------- Scan pass B: inter-chunk scan; rewrites P <- carry-in ----
__global__ __launch_bounds__(256) void scanB_kernel(float* __restrict__ P,
                                                    const float* __restrict__ H,
                                                    int nchunk) {
    const int t = blockIdx.x * 256 + threadIdx.x;   // (b*1024+d)*16+n
    const size_t cs = (size_t)BATCH * D_MODEL * D_STATE;
    float carry = 0.0f;
    float p_c = P[t], h_c = H[t];
    for (int c = 0; c < nchunk; ++c) {
        float p_n = 0.0f, h_n = 0.0f;
        if (c + 1 < nchunk) {                       // prefetch next chunk
            p_n = P[(size_t)(c + 1) * cs + t];
            h_n = H[(size_t)(c + 1) * cs + t];
        }
        P[(size_t)c * cs + t] = carry;              // carry-in for this chunk
        carry = fmaf(p_c, carry, h_c);
        p_c = p_n; h_c = h_n;
    }
}

// ---------------- Scan pass C: replay with carry-in, produce y -------------
template<int CLEN_T>
__global__ __launch_bounds__(256) void scanC_kernel(const float* __restrict__ x,
                                                    const float* __restrict__ xp,
                                                    const float* __restrict__ delta,
                                                    const float* __restrict__ A_log,
                                                    const float* __restrict__ Dvec,
                                                    const float* __restrict__ Hin,
                                                    float* __restrict__ out) {
    const int chunk = blockIdx.x;
    const int b     = blockIdx.z;
    const int d     = blockIdx.y * 256 + threadIdx.x;

    float Av[16];
    const float4* Arow = reinterpret_cast<const float4*>(A_log + (size_t)d * D_STATE);
#pragma unroll
    for (int q = 0; q < 4; ++q) {
        float4 v = Arow[q];
        Av[q*4+0] = -__expf(v.x); Av[q*4+1] = -__expf(v.y);
        Av[q*4+2] = -__expf(v.z); Av[q*4+3] = -__expf(v.w);
    }
    const float Dv = Dvec[d];

    float h[16];
    size_t idx = (((size_t)chunk * BATCH + b) * D_MODEL + d) * D_STATE;
    const float4* Hp = reinterpret_cast<const float4*>(Hin + idx);
#pragma unroll
    for (int q = 0; q < 4; ++q) {
        float4 v = Hp[q];
        h[q*4+0] = v.x; h[q*4+1] = v.y; h[q*4+2] = v.z; h[q*4+3] = v.w;
    }

    const size_t m0 = (size_t)b * SEQ + (size_t)chunk * CLEN_T;
    const size_t xbase = m0 * D_MODEL + d;
    const size_t pbase = m0 * NPROJ + DT_RANK;

    float dv_c = delta[xbase];
    float xv_c = x[xbase];
#pragma unroll 4
    for (int j = 0; j < CLEN_T; ++j) {
        float dv_n = 0.0f, xv_n = 0.0f;
        if (j + 1 < CLEN_T) {                      // prefetch next step
            dv_n = delta[xbase + (size_t)(j + 1) * D_MODEL];
            xv_n = x[xbase + (size_t)(j + 1) * D_MODEL];
        }
        const float4* Bp = reinterpret_cast<const float4*>(xp + pbase + (size_t)j * NPROJ);
        float4 B0 = Bp[0], B1 = Bp[1], B2 = Bp[2], B3 = Bp[3];
        float4 C0 = Bp[4], C1 = Bp[5], C2 = Bp[6], C3 = Bp[7];
        float Bv[16] = {B0.x,B0.y,B0.z,B0.w, B1.x,B1.y,B1.z,B1.w,
                        B2.x,B2.y,B2.z,B2.w, B3.x,B3.y,B3.z,B3.w};
        float Cv[16] = {C0.x,C0.y,C0.z,C0.w, C1.x,C1.y,C1.z,C1.w,
                        C2.x,C2.y,C2.z,C2.w, C3.x,C3.y,C3.z,C3.w};
        float dtx = dv_c * xv_c;
        float y = 0.0f;
#pragma unroll
        for (int n = 0; n < 16; ++n) {
            float a = __expf(dv_c * Av[n]);
            h[n] = fmaf(a, h[n], dtx * Bv[n]);
            y = fmaf(h[n], Cv[n], y);
        }
        out[xbase + (size_t)j * D_MODEL] = fmaf(xv_c, Dv, y);
        dv_c = dv_n; xv_c = xv_n;
    }
}

extern "C" void kernel_launch(void* const* d_in, const int* in_sizes, int n_in,
                              void* d_out, int out_size, void* d_ws, size_t ws_size,
                              hipStream_t stream) {
    const float* x    = (const float*)d_in[0];
    const float* Wx   = (const float*)d_in[1];
    const float* Wd   = (const float*)d_in[2];
    const float* bdt  = (const float*)d_in[3];
    const float* Alog = (const float*)d_in[4];
    const float* Dv   = (const float*)d_in[5];
    float* out = (float*)d_out;

    // ---- workspace layout (floats) ----
    float* ws    = (float*)d_ws;
    float* xp    = ws;                                        // 1.57M
    float* delta = xp + (size_t)M_TOTAL * NPROJ;              // 16.78M
    float* scan0 = delta + (size_t)M_TOTAL * D_MODEL;         // P | H (part aliases)
    float* part  = scan0;

    const size_t baseF = (size_t)M_TOTAL * NPROJ + (size_t)M_TOTAL * D_MODEL;
    const size_t chunkF = (size_t)BATCH * D_MODEL * D_STATE;  // per-chunk P or H floats

    // choose config by available workspace (ws_size constant -> capture-safe)
    int ksplit, nchunk;
    size_t needA = (baseF + 2 * 128 * chunkF) * 4;            // ~140.5 MB
    size_t needB = (baseF + (size_t)8 * M_TOTAL * NPROJ) * 4; // ~123.7 MB
    if (ws_size >= needA)      { ksplit = 8; nchunk = 128; }
    else if (ws_size >= needB) { ksplit = 8; nchunk = 64;  }
    else                       { ksplit = 4; nchunk = 64;  }

    float* P = scan0;
    float* H = scan0 + (size_t)nchunk * chunkF;

    proj_part_kernel<<<dim3(M_TOTAL / 64, ksplit), 256, 0, stream>>>(x, Wx, part, 1024 / ksplit);
    reduce_xp_kernel<<<dim3((M_TOTAL * NPROJ / 4) / 256), 256, 0, stream>>>(part, xp, ksplit);
    delta_kernel<<<dim3(M_TOTAL / 128, D_MODEL / 128), 256, 0, stream>>>(xp, Wd, bdt, delta);
    if (nchunk == 128) {
        scanA_kernel<32><<<dim3(128, 4, BATCH), 256, 0, stream>>>(x, xp, delta, Alog, P, H);
        scanB_kernel<<<dim3(256), 256, 0, stream>>>(P, H, 128);
        scanC_kernel<32><<<dim3(128, 4, BATCH), 256, 0, stream>>>(x, xp, delta, Alog, Dv, P, out);
    } else {
        scanA_kernel<64><<<dim3(64, 4, BATCH), 256, 0, stream>>>(x, xp, delta, Alog, P, H);
        scanB_kernel<<<dim3(256), 256, 0, stream>>>(P, H, 64);
        scanC_kernel<64><<<dim3(64, 4, BATCH), 256, 0, stream>>>(x, xp, delta, Alog, Dv, P, out);
    }
}

// Round 7
// 347.397 us; speedup vs baseline: 1.0057x; 1.0057x over previous
//
#include <hip/hip_runtime.h>
#include <cstddef>

#define D_MODEL 1024
#define D_STATE 16
#define DT_RANK 64
#define BATCH 4
#define SEQ 4096
#define NPROJ 96                 // DT_RANK + 2*D_STATE
#define M_TOTAL (BATCH * SEQ)    // 16384
#define NCHUNK 64
#define CLEN 64                  // SEQ / NCHUNK
#define KSPLIT 4
#define KSLICE 256               // 1024 / KSPLIT

typedef __attribute__((ext_vector_type(8))) short bf16x8;
typedef __attribute__((ext_vector_type(4))) short short4v;
typedef __attribute__((ext_vector_type(4))) float f32x4;

__device__ __forceinline__ float softplus_fast(float v) {
    return fmaxf(v, 0.0f) + __logf(1.0f + __expf(-fabsf(v)));
}

// float -> bf16 (RNE), and back
__device__ __forceinline__ short f2bf(float x) {
    union { float f; unsigned u; } v; v.f = x;
    unsigned r = (v.u + 0x7fffu + ((v.u >> 16) & 1u)) >> 16;
    return (short)r;
}
__device__ __forceinline__ float bf2f(short s) {
    union { unsigned u; float f; } v; v.u = ((unsigned)(unsigned short)s) << 16;
    return v.f;
}
struct bfpair { short hi, lo; };
__device__ __forceinline__ bfpair split_bf(float x) {
    bfpair r;
    r.hi = f2bf(x);
    r.lo = f2bf(x - bf2f(r.hi));
    return r;
}
// split a float4 into hi/lo short4v packs
__device__ __forceinline__ void split_bf4(float4 v, short4v& h, short4v& l) {
    bfpair a = split_bf(v.x), b = split_bf(v.y), c = split_bf(v.z), d = split_bf(v.w);
    h = (short4v){a.hi, b.hi, c.hi, d.hi};
    l = (short4v){a.lo, b.lo, c.lo, d.lo};
}

// ---------------- GEMM1 (split-K, MFMA hi/lo): part[ks][m,p] ----------------
// BM=64, BN=96 (full), BK=32, kslice=256. 256 thr = 4 waves; wave w owns a
// 16-row slice x 96 cols (6 col-frags of 16x16x32 bf16 MFMA).
__global__ __launch_bounds__(256) void proj_mfma_kernel(const float* __restrict__ x,
                                                        const float* __restrict__ W,
                                                        float* __restrict__ part) {
    __shared__ short ah[64][40], al[64][40];   // x tile hi/lo, stride 40 (80B, 16B-aligned)
    __shared__ short bh[96][40], bl[96][40];   // W tile hi/lo
    const int tid   = threadIdx.x;
    const int row0  = blockIdx.x * 64;
    const int kbase = blockIdx.y * KSLICE;
    const int wid   = tid >> 6;
    const int lane  = tid & 63;
    const int l16   = lane & 15;
    const int kg    = lane >> 4;            // 0..3 -> k-offset kg*8

    f32x4 acc[6];
#pragma unroll
    for (int c = 0; c < 6; ++c) acc[c] = (f32x4){0.f, 0.f, 0.f, 0.f};

    for (int k0 = kbase; k0 < kbase + KSLICE; k0 += 32) {
        // stage x: 64 rows x 32 k (512 float4, 2/thread)
        for (int i = tid; i < 64 * 8; i += 256) {
            int r = i >> 3, c4 = i & 7;
            float4 v = *reinterpret_cast<const float4*>(
                &x[(size_t)(row0 + r) * 1024 + k0 + c4 * 4]);
            short4v h, l;
            split_bf4(v, h, l);
            *reinterpret_cast<short4v*>(&ah[r][c4 * 4]) = h;
            *reinterpret_cast<short4v*>(&al[r][c4 * 4]) = l;
        }
        // stage W: 96 rows x 32 k (768 float4, 3/thread)
        for (int i = tid; i < 96 * 8; i += 256) {
            int r = i >> 3, c4 = i & 7;
            float4 v = *reinterpret_cast<const float4*>(
                &W[(size_t)r * 1024 + k0 + c4 * 4]);
            short4v h, l;
            split_bf4(v, h, l);
            *reinterpret_cast<short4v*>(&bh[r][c4 * 4]) = h;
            *reinterpret_cast<short4v*>(&bl[r][c4 * 4]) = l;
        }
        __syncthreads();

        bf16x8 a_h = *reinterpret_cast<const bf16x8*>(&ah[wid * 16 + l16][kg * 8]);
        bf16x8 a_l = *reinterpret_cast<const bf16x8*>(&al[wid * 16 + l16][kg * 8]);
#pragma unroll
        for (int c = 0; c < 6; ++c) {
            bf16x8 b_h = *reinterpret_cast<const bf16x8*>(&bh[c * 16 + l16][kg * 8]);
            bf16x8 b_l = *reinterpret_cast<const bf16x8*>(&bl[c * 16 + l16][kg * 8]);
            acc[c] = __builtin_amdgcn_mfma_f32_16x16x32_bf16(a_h, b_h, acc[c], 0, 0, 0);
            acc[c] = __builtin_amdgcn_mfma_f32_16x16x32_bf16(a_h, b_l, acc[c], 0, 0, 0);
            acc[c] = __builtin_amdgcn_mfma_f32_16x16x32_bf16(a_l, b_h, acc[c], 0, 0, 0);
        }
        __syncthreads();
    }
    // D layout: col = lane&15, row = (lane>>4)*4 + q   [m89-verified]
    size_t base = ((size_t)blockIdx.y * M_TOTAL + row0 + wid * 16 + kg * 4) * NPROJ;
#pragma unroll
    for (int c = 0; c < 6; ++c) {
#pragma unroll
        for (int q = 0; q < 4; ++q)
            part[base + (size_t)q * NPROJ + c * 16 + l16] = acc[c][q];
    }
}

// ---------------- reduce: xp = sum_ks part[ks]  (float4 grid) ----------------
__global__ __launch_bounds__(256) void reduce_xp_kernel(const float* __restrict__ part,
                                                        float* __restrict__ xp) {
    const size_t stride4 = (size_t)M_TOTAL * NPROJ / 4;
    size_t i = (size_t)blockIdx.x * 256 + threadIdx.x;
    const float4* p = reinterpret_cast<const float4*>(part);
    float4 a = p[i];
#pragma unroll
    for (int s = 1; s < KSPLIT; ++s) {
        float4 b = p[i + (size_t)s * stride4];
        a.x += b.x; a.y += b.y; a.z += b.z; a.w += b.w;
    }
    reinterpret_cast<float4*>(xp)[i] = a;
}

// ------- GEMM2 (MFMA hi/lo): delta[m,d] = softplus(xp[:, :64]*Wd^T + b) -----
// BM=64, BN=64, K=64 (2 MFMA k-steps, staged once). 256 thr = 4 waves;
// wave w owns 16 rows x 64 cols (4 col-frags).
__global__ __launch_bounds__(256) void delta_mfma_kernel(const float* __restrict__ xp,
                                                         const float* __restrict__ Wd,
                                                         const float* __restrict__ b_dt,
                                                         float* __restrict__ delta) {
    __shared__ short ah[64][72], al[64][72];   // xp tile hi/lo (stride 72 = 144B)
    __shared__ short bh[64][72], bl[64][72];   // Wd tile hi/lo
    const int tid  = threadIdx.x;
    const int row0 = blockIdx.x * 64;
    const int col0 = blockIdx.y * 64;
    const int wid  = tid >> 6;
    const int lane = tid & 63;
    const int l16  = lane & 15;
    const int kg   = lane >> 4;

    // stage xp rows (first 64 of 96) and Wd rows: 64x64 each, 4 float4/thread
    for (int i = tid; i < 64 * 16; i += 256) {
        int r = i >> 4, c4 = i & 15;
        float4 v = *reinterpret_cast<const float4*>(
            &xp[(size_t)(row0 + r) * NPROJ + c4 * 4]);
        short4v h, l;
        split_bf4(v, h, l);
        *reinterpret_cast<short4v*>(&ah[r][c4 * 4]) = h;
        *reinterpret_cast<short4v*>(&al[r][c4 * 4]) = l;
    }
    for (int i = tid; i < 64 * 16; i += 256) {
        int r = i >> 4, c4 = i & 15;
        float4 v = *reinterpret_cast<const float4*>(
            &Wd[(size_t)(col0 + r) * 64 + c4 * 4]);
        short4v h, l;
        split_bf4(v, h, l);
        *reinterpret_cast<short4v*>(&bh[r][c4 * 4]) = h;
        *reinterpret_cast<short4v*>(&bl[r][c4 * 4]) = l;
    }
    __syncthreads();

    f32x4 acc[4];
#pragma unroll
    for (int j = 0; j < 4; ++j) acc[j] = (f32x4){0.f, 0.f, 0.f, 0.f};

#pragma unroll
    for (int ks = 0; ks < 2; ++ks) {
        int koff = ks * 32 + kg * 8;
        bf16x8 a_h = *reinterpret_cast<const bf16x8*>(&ah[wid * 16 + l16][koff]);
        bf16x8 a_l = *reinterpret_cast<const bf16x8*>(&al[wid * 16 + l16][koff]);
#pragma unroll
        for (int j = 0; j < 4; ++j) {
            bf16x8 b_h = *reinterpret_cast<const bf16x8*>(&bh[j * 16 + l16][koff]);
            bf16x8 b_l = *reinterpret_cast<const bf16x8*>(&bl[j * 16 + l16][koff]);
            acc[j] = __builtin_amdgcn_mfma_f32_16x16x32_bf16(a_h, b_h, acc[j], 0, 0, 0);
            acc[j] = __builtin_amdgcn_mfma_f32_16x16x32_bf16(a_h, b_l, acc[j], 0, 0, 0);
            acc[j] = __builtin_amdgcn_mfma_f32_16x16x32_bf16(a_l, b_h, acc[j], 0, 0, 0);
        }
    }

    int row = row0 + wid * 16 + kg * 4;
#pragma unroll
    for (int j = 0; j < 4; ++j) {
        int col = col0 + j * 16 + l16;
        float bias = b_dt[col];
#pragma unroll
        for (int q = 0; q < 4; ++q)
            delta[(size_t)(row + q) * D_MODEL + col] = softplus_fast(acc[j][q] + bias);
    }
}

// ---------------- Scan pass A: per-chunk transfer (exp2(Av2*sum_dv), h) -----
__global__ __launch_bounds__(256) void scanA_kernel(const float* __restrict__ x,
                                                    const float* __restrict__ xp,
                                                    const float* __restrict__ delta,
                                                    const float* __restrict__ A_log,
                                                    float* __restrict__ P,
                                                    float* __restrict__ H) {
    const int chunk = blockIdx.x;
    const int b     = blockIdx.z;
    const int d     = blockIdx.y * 256 + threadIdx.x;
    const float LOG2E = 1.4426950408889634f;

    float Av[16];   // pre-scaled by log2(e): a = exp2(dv*Av[n])
    const float4* Arow = reinterpret_cast<const float4*>(A_log + (size_t)d * D_STATE);
#pragma unroll
    for (int q = 0; q < 4; ++q) {
        float4 v = Arow[q];
        Av[q*4+0] = -__expf(v.x) * LOG2E; Av[q*4+1] = -__expf(v.y) * LOG2E;
        Av[q*4+2] = -__expf(v.z) * LOG2E; Av[q*4+3] = -__expf(v.w) * LOG2E;
    }
    float h[16];
#pragma unroll
    for (int n = 0; n < 16; ++n) h[n] = 0.0f;
    float sdv = 0.0f;

    const size_t m0 = (size_t)b * SEQ + (size_t)chunk * CLEN;
    const size_t xbase = m0 * D_MODEL + d;
    const size_t pbase = m0 * NPROJ + DT_RANK;

#pragma unroll 2
    for (int j = 0; j < CLEN; ++j) {
        float dv = delta[xbase + (size_t)j * D_MODEL];
        float xv = x[xbase + (size_t)j * D_MODEL];
        float dtx = dv * xv;
        const float4* Bp = reinterpret_cast<const float4*>(xp + pbase + (size_t)j * NPROJ);
        float4 B0 = Bp[0], B1 = Bp[1], B2 = Bp[2], B3 = Bp[3];
        float Bv[16] = {B0.x,B0.y,B0.z,B0.w, B1.x,B1.y,B1.z,B1.w,
                        B2.x,B2.y,B2.z,B2.w, B3.x,B3.y,B3.z,B3.w};
        sdv += dv;
#pragma unroll
        for (int n = 0; n < 16; ++n) {
            float a = exp2f(dv * Av[n]);
            h[n] = fmaf(a, h[n], dtx * Bv[n]);
        }
    }
    size_t idx = (((size_t)chunk * BATCH + b) * D_MODEL + d) * D_STATE;
    float4* Pp = reinterpret_cast<float4*>(P + idx);
    float4* Hp = reinterpret_cast<float4*>(H + idx);
#pragma unroll
    for (int q = 0; q < 4; ++q) {
        float4 pv, hv;
        pv.x = exp2f(Av[q*4+0] * sdv); pv.y = exp2f(Av[q*4+1] * sdv);
        pv.z = exp2f(Av[q*4+2] * sdv); pv.w = exp2f(Av[q*4+3] * sdv);
        hv.x = h[q*4+0]; hv.y = h[q*4+1]; hv.z = h[q*4+2]; hv.w = h[q*4+3];
        Pp[q] = pv; Hp[q] = hv;
    }
}

// ---------------- Scan pass B: inter-chunk scan; rewrites P <- carry-in ----
__global__ __launch_bounds__(256) void scanB_kernel(float* __restrict__ P,
                                                    const float* __restrict__ H) {
    const int t = blockIdx.x * 256 + threadIdx.x;
    float carry = 0.0f;
    for (int c = 0; c < NCHUNK; ++c) {
        size_t idx = (size_t)c * (BATCH * D_MODEL * D_STATE) + t;
        float p  = P[idx];
        float hh = H[idx];
        P[idx] = carry;
        carry = fmaf(p, carry, hh);
    }
}

// ---------------- Scan pass C: replay with carry-in, produce y -------------
__global__ __launch_bounds__(256) void scanC_kernel(const float* __restrict__ x,
                                                    const float* __restrict__ xp,
                                                    const float* __restrict__ delta,
                                                    const float* __restrict__ A_log,
                                                    const float* __restrict__ Dvec,
                                                    const float* __restrict__ Hin,
                                                    float* __restrict__ out) {
    const int chunk = blockIdx.x;
    const int b     = blockIdx.z;
    const int d     = blockIdx.y * 256 + threadIdx.x;
    const float LOG2E = 1.4426950408889634f;

    float Av[16];
    const float4* Arow = reinterpret_cast<const float4*>(A_log + (size_t)d * D_STATE);
#pragma unroll
    for (int q = 0; q < 4; ++q) {
        float4 v = Arow[q];
        Av[q*4+0] = -__expf(v.x) * LOG2E; Av[q*4+1] = -__expf(v.y) * LOG2E;
        Av[q*4+2] = -__expf(v.z) * LOG2E; Av[q*4+3] = -__expf(v.w) * LOG2E;
    }
    const float Dv = Dvec[d];

    float h[16];
    size_t idx = (((size_t)chunk * BATCH + b) * D_MODEL + d) * D_STATE;
    const float4* Hp = reinterpret_cast<const float4*>(Hin + idx);
#pragma unroll
    for (int q = 0; q < 4; ++q) {
        float4 v = Hp[q];
        h[q*4+0] = v.x; h[q*4+1] = v.y; h[q*4+2] = v.z; h[q*4+3] = v.w;
    }

    const size_t m0 = (size_t)b * SEQ + (size_t)chunk * CLEN;
    const size_t xbase = m0 * D_MODEL + d;
    const size_t pbase = m0 * NPROJ + DT_RANK;

#pragma unroll 2
    for (int j = 0; j < CLEN; ++j) {
        float dv = delta[xbase + (size_t)j * D_MODEL];
        float xv = x[xbase + (size_t)j * D_MODEL];
        float dtx = dv * xv;
        const float4* Bp = reinterpret_cast<const float4*>(xp + pbase + (size_t)j * NPROJ);
        float4 B0 = Bp[0], B1 = Bp[1], B2 = Bp[2], B3 = Bp[3];
        float4 C0 = Bp[4], C1 = Bp[5], C2 = Bp[6], C3 = Bp[7];
        float Bv[16] = {B0.x,B0.y,B0.z,B0.w, B1.x,B1.y,B1.z,B1.w,
                        B2.x,B2.y,B2.z,B2.w, B3.x,B3.y,B3.z,B3.w};
        float Cv[16] = {C0.x,C0.y,C0.z,C0.w, C1.x,C1.y,C1.z,C1.w,
                        C2.x,C2.y,C2.z,C2.w, C3.x,C3.y,C3.z,C3.w};
        float y = 0.0f;
#pragma unroll
        for (int n = 0; n < 16; ++n) {
            float a = exp2f(dv * Av[n]);
            h[n] = fmaf(a, h[n], dtx * Bv[n]);
            y = fmaf(h[n], Cv[n], y);
        }
        out[xbase + (size_t)j * D_MODEL] = fmaf(xv, Dv, y);
    }
}

extern "C" void kernel_launch(void* const* d_in, const int* in_sizes, int n_in,
                              void* d_out, int out_size, void* d_ws, size_t ws_size,
                              hipStream_t stream) {
    const float* x    = (const float*)d_in[0];
    const float* Wx   = (const float*)d_in[1];
    const float* Wd   = (const float*)d_in[2];
    const float* bdt  = (const float*)d_in[3];
    const float* Alog = (const float*)d_in[4];
    const float* Dv   = (const float*)d_in[5];
    float* out = (float*)d_out;

    float* ws    = (float*)d_ws;
    float* xp    = ws;                                        // 16384*96
    float* delta = xp + (size_t)M_TOTAL * NPROJ;              // 16384*1024
    float* scan0 = delta + (size_t)M_TOTAL * D_MODEL;
    float* part  = scan0;   // 4*16384*96 = 25.2 MB, dead before P/H written
    float* P     = scan0;
    float* H     = scan0 + (size_t)NCHUNK * BATCH * D_MODEL * D_STATE;

    proj_mfma_kernel<<<dim3(M_TOTAL / 64, KSPLIT), 256, 0, stream>>>(x, Wx, part);
    reduce_xp_kernel<<<dim3((M_TOTAL * NPROJ / 4) / 256), 256, 0, stream>>>(part, xp);
    delta_mfma_kernel<<<dim3(M_TOTAL / 64, D_MODEL / 64), 256, 0, stream>>>(xp, Wd, bdt, delta);
    scanA_kernel<<<dim3(NCHUNK, 4, BATCH), 256, 0, stream>>>(x, xp, delta, Alog, P, H);
    scanB_kernel<<<dim3((BATCH * D_MODEL * D_STATE) / 256), 256, 0, stream>>>(P, H);
    scanC_kernel<<<dim3(NCHUNK, 4, BATCH), 256, 0, stream>>>(x, xp, delta, Alog, Dv, P, out);
}